// Round 10
// baseline (228.494 us; speedup 1.0000x reference)
//
#include <hip/hip_runtime.h>
#include <math.h>

// Problem constants
#define BDIM 4
#define GDIM 40
#define CDIM 13
#define TDIM 1024
#define FDIM 513                 // T/2 + 1
#define BG   (BDIM*GDIM)         // 160
#define NROW (BG*FDIM)           // 82080 rows of [13] complex
#define NCHUNK 9                 // 9*64 = 576 >= 513 q-rows per bg

typedef _Float16 half4 __attribute__((ext_vector_type(4)));
typedef _Float16 half8 __attribute__((ext_vector_type(8)));
typedef float    f32x4 __attribute__((ext_vector_type(4)));

#define MFMA16(a, b, c) __builtin_amdgcn_mfma_f32_16x16x16f16((a), (b), (c), 0, 0, 0)
#define MFMA32(a, b, c) __builtin_amdgcn_mfma_f32_16x16x32_f16((a), (b), (c), 0, 0, 0)
// Scheduling fence: ALU/VALU/SALU/MFMA may cross (mask 0xF), VMEM/DS may NOT.
// Pins prefetch loads above the fence without constraining compute scheduling
// (avoids the full-pin regression mode of sched_barrier(0)).
#define SBAR() __builtin_amdgcn_sched_barrier(0x0F)

__device__ __forceinline__ unsigned bitrev10(unsigned x) { return __brev(x) >> 22; }

// ---------------- Kernel 1: two-for-one rfft(1024) ----------------
// Launched with 512 threads: 1 butterfly per thread per stage, 8 waves/block.
__global__ void fft_fwd2(const float* __restrict__ x, float2* __restrict__ xf) {
    __shared__ float re[1024], im[1024];
    const int s2 = blockIdx.x;                   // pair index, 0..1039
    const float* x1 = x + (size_t)(2 * s2) * TDIM;
    const float* x2 = x1 + TDIM;
    for (int t = threadIdx.x; t < 1024; t += blockDim.x) {
        unsigned r = bitrev10(t);
        re[r] = x1[t];
        im[r] = x2[t];
    }
    __syncthreads();
    for (int s = 0; s < 10; ++s) {
        int half = 1 << s;
        for (int j = threadIdx.x; j < 512; j += blockDim.x) {
            int grp = j >> s;
            int pos = j & (half - 1);
            int i1 = (grp << (s + 1)) + pos;
            int i2 = i1 + half;
            float ang = -(float)M_PI * (float)pos / (float)half;
            float sw, cw; __sincosf(ang, &sw, &cw);
            float xr = re[i2], xi = im[i2];
            float tr = cw * xr - sw * xi;
            float ti = cw * xi + sw * xr;
            float ur = re[i1], ui = im[i1];
            re[i1] = ur + tr; im[i1] = ui + ti;
            re[i2] = ur - tr; im[i2] = ui - ti;
        }
        __syncthreads();
    }
    const int sigA = 2 * s2, sigB = sigA + 1;
    const int bgA = sigA / CDIM, cA = sigA % CDIM;
    const int bgB = sigB / CDIM, cB = sigB % CDIM;
    for (int f = threadIdx.x; f < FDIM; f += blockDim.x) {
        int fr = (1024 - f) & 1023;
        float zr = re[f], zi = im[f];
        float wr = re[fr], wi = im[fr];
        xf[((size_t)bgA * FDIM + f) * CDIM + cA] =
            make_float2(0.5f * (zr + wr), 0.5f * (zi - wi));
        xf[((size_t)bgB * FDIM + f) * CDIM + cB] =
            make_float2(0.5f * (zi + wi), 0.5f * (wr - zr));
    }
}

// ---------------- Kernel 2: Q/K/V projections ----------------
// q: float2 rows (for in-reg Q-fragment build in attn).
// KP: per row 64 halves [hi(kr)0..12 | hi(ki)@13..25 | 0 @26..31 | lo(kr)@32..44 | lo(ki)@45..57 | 0 @58..63]
// VT: fp16, transposed: [bg][re/im][c(16)][f stride 520]
__global__ void qkv_kernel(const float2* __restrict__ xf,
                           const float* __restrict__ wq,
                           const float* __restrict__ wk,
                           const float* __restrict__ wv,
                           float2* __restrict__ q,
                           _Float16* __restrict__ KP,
                           _Float16* __restrict__ VT) {
    int gid = blockIdx.x * blockDim.x + threadIdx.x;
    if (gid >= NROW * CDIM) return;
    int r = gid / CDIM;
    int i = gid - r * CDIM;
    const float2* xrow = xf + (size_t)r * CDIM;
    float qr = 0, qi = 0, kr = 0, ki = 0, vr = 0, vi = 0;
#pragma unroll
    for (int c = 0; c < CDIM; ++c) {
        float2 xc = xrow[c];
        float a = wq[c * CDIM + i]; qr += xc.x * a; qi += xc.y * a;
        float b = wk[c * CDIM + i]; kr += xc.x * b; ki += xc.y * b;
        float d = wv[c * CDIM + i]; vr += xc.x * d; vi += xc.y * d;
    }
    q[gid] = make_float2(qr, qi);

    _Float16* krow = KP + (size_t)r * 64;
    _Float16 h0 = (_Float16)kr;
    _Float16 h1 = (_Float16)ki;
    krow[i]      = h0;
    krow[13 + i] = h1;
    krow[32 + i] = (_Float16)(kr - (float)h0);
    krow[45 + i] = (_Float16)(ki - (float)h1);
    if (i == 12) {   // zero the pad halves 26..31 and 58..63
        *(unsigned int*)(krow + 26) = 0u;
        *(unsigned int*)(krow + 28) = 0u;
        *(unsigned int*)(krow + 30) = 0u;
        *(unsigned int*)(krow + 58) = 0u;
        *(unsigned int*)(krow + 60) = 0u;
        *(unsigned int*)(krow + 62) = 0u;
    }
    int bg = r / FDIM;
    int f  = r - bg * FDIM;
    VT[((size_t)(bg * 2 + 0) * 16 + i) * 520 + f] = (_Float16)vr;
    VT[((size_t)(bg * 2 + 1) * 16 + i) * 520 + f] = (_Float16)vi;
}

// ---------------- Kernel 3: MFMA flash attention (no-LDS, pinned 2-deep pipeline) ----------------
// r8/r9 lessons: direct-global fragments give minimal HBM traffic (FETCH 13 MB, L2-
// pinned, zero barriers) but hipcc SINKS unsupported register prefetch back to uses
// (r9: VGPR fell to 40, dur flat 113us) -> load latency fully exposed. This round:
//  (a) distance-2 prefetch with SBAR() fences (VMEM cannot sink, compute stays free);
//  (b) shfl-free common path: __all(local_max <= m+8) ballot first; the 2 cross-lane
//      shfl_xor max reductions run ONLY inside the rarely-taken rescale branch.
//      m stays row-uniform (branch wave-uniform, new m = max(uniform m, row max));
//      p <= 2^8 bound unchanged -> identical softmax semantics, ~60 serial cyc less
//      per sub-step and exp2 no longer waits on DS ops.
// Everything else as r8: barrier-free, no LDS, XCD-pinned (bg = bid % 160, 160%8==0),
// log2-domain softmax, tail key 512 guarded.
// PRE-COMMIT: if dur stays ~113 AND VGPR <= 48, hipcc defeats reg pipelining here ->
// revert to the r2 staged structure (81.4 us known-good) next round.
__device__ __forceinline__ void attn_step(
    half4 a0, half4 a1, half4 a2, half4 a3, half4 vfr, half4 vfi,
    const half8& Quh, const half8& Qul, const half8& Qu2h, const half8& Qu2l,
    f32x4& ore, f32x4& oim, float& m, float& l)
{
    half8 whh, wll;
#pragma unroll
    for (int j = 0; j < 4; ++j) {
        whh[j] = a0[j]; whh[4 + j] = a1[j];
        wll[j] = a2[j]; wll[4 + j] = a3[j];
    }
    f32x4 sre = {0.f, 0.f, 0.f, 0.f};
    f32x4 sim = {0.f, 0.f, 0.f, 0.f};
    sre = MFMA32(whh, Quh, sre);
    sre = MFMA32(wll, Quh, sre);
    sre = MFMA32(whh, Qul, sre);
    sre = MFMA32(wll, Qul, sre);
    sim = MFMA32(whh, Qu2h, sim);
    sim = MFMA32(wll, Qu2h, sim);
    sim = MFMA32(whh, Qu2l, sim);
    sim = MFMA32(wll, Qu2l, sim);
    float s0 = sqrtf(fmaf(sre[0], sre[0], sim[0] * sim[0]));
    float s1 = sqrtf(fmaf(sre[1], sre[1], sim[1] * sim[1]));
    float s2 = sqrtf(fmaf(sre[2], sre[2], sim[2] * sim[2]));
    float s3 = sqrtf(fmaf(sre[3], sre[3], sim[3] * sim[3]));
    float tm = fmaxf(fmaxf(s0, s1), fmaxf(s2, s3));   // lane-local max
    if (!__all(tm <= m + 8.f)) {          // rare: rescale needed somewhere in wave
        tm = fmaxf(tm, __shfl_xor(tm, 16));
        tm = fmaxf(tm, __shfl_xor(tm, 32));           // row max (uniform per column)
        float mnew  = fmaxf(m, tm);
        float alpha = exp2f(m - mnew);    // exp2(-inf)=0 covers first step
        l *= alpha; ore *= alpha; oim *= alpha;
        m = mnew;
    }
    float p0 = exp2f(s0 - m);
    float p1 = exp2f(s1 - m);
    float p2 = exp2f(s2 - m);
    float p3 = exp2f(s3 - m);
    l += (p0 + p1) + (p2 + p3);
    half4 pk;
    pk[0] = (_Float16)p0; pk[1] = (_Float16)p1;
    pk[2] = (_Float16)p2; pk[3] = (_Float16)p3;
    ore = MFMA16(vfr, pk, ore);
    oim = MFMA16(vfi, pk, oim);
}

__device__ __forceinline__ void load_frag(
    const _Float16* __restrict__ KPg, const _Float16* __restrict__ VTg,
    int s, int qlane, int g,
    half4& a0, half4& a1, half4& a2, half4& a3, half4& vfr, half4& vfi)
{
    const int arow = s * 16 + qlane;
    const _Float16* kr = KPg + arow * 64 + 4 * g;
    a0 = *(const half4*)(kr);
    a1 = *(const half4*)(kr + 16);
    a2 = *(const half4*)(kr + 32);
    a3 = *(const half4*)(kr + 48);
    const int f0 = s * 16 + 4 * g;
    vfr = *(const half4*)(VTg + qlane * 520 + f0);
    vfi = *(const half4*)(VTg + (16 + qlane) * 520 + f0);
}

__global__ __launch_bounds__(256, 4) void attn_kernel(const float2* __restrict__ q,
                                                      const _Float16* __restrict__ KP,
                                                      const _Float16* __restrict__ VT,
                                                      float2* __restrict__ outspec) {
    const int bg    = blockIdx.x % BG;           // XCD-pinned: bid%8 == bg%8
    const int chunk = blockIdx.x / BG;
    const int tid   = threadIdx.x;
    const int w     = tid >> 6;
    const int lane  = tid & 63;
    const int qlane = lane & 15;
    const int g     = lane >> 4;
    const int frow  = chunk * 64 + w * 16 + qlane;
    const bool writer = (frow < FDIM);
    const int f     = writer ? frow : (FDIM - 1);
    const size_t rowbase = ((size_t)bg * FDIM + f) * CDIM;

    // ---- build Q fragments (scaled by log2e): u=[qr,-qi], u'=[qi,qr] ----
    const float LOG2E = 1.44269504088896340736f;
    half8 Quh, Qul, Qu2h, Qu2l;
#pragma unroll
    for (int c = 0; c < 2; ++c) {
#pragma unroll
        for (int j = 0; j < 4; ++j) {
            const int e = 4 * c + j;
            const int k = 16 * c + 4 * g + j;
            float a = 0.f, b = 0.f;
            if (k < CDIM) {
                float2 t = q[rowbase + k];          a = t.x;  b = t.y;
            } else if (k < 2 * CDIM) {
                float2 t = q[rowbase + (k - CDIM)]; a = -t.y; b = t.x;
            }
            a *= LOG2E;
            b *= LOG2E;
            _Float16 ah = (_Float16)a;
            Quh[e]  = ah;
            Qul[e]  = (_Float16)(a - (float)ah);
            _Float16 bh = (_Float16)b;
            Qu2h[e] = bh;
            Qu2l[e] = (_Float16)(b - (float)bh);
        }
    }

    f32x4 ore = {0.f, 0.f, 0.f, 0.f};
    f32x4 oim = {0.f, 0.f, 0.f, 0.f};
    float m = -INFINITY, l = 0.f;

    const _Float16* __restrict__ KPg = KP + (size_t)bg * FDIM * 64;
    const _Float16* __restrict__ VTg = VT + (size_t)bg * 2 * 16 * 520;

    // ---- pinned distance-2 pipeline over the 32 full sub-steps (keys 0..511) ----
    half4 pa0, pa1, pa2, pa3, pvr, pvi;          // even buffer
    half4 qa0, qa1, qa2, qa3, qvr, qvi;          // odd buffer
    load_frag(KPg, VTg, 0, qlane, g, pa0, pa1, pa2, pa3, pvr, pvi);
    load_frag(KPg, VTg, 1, qlane, g, qa0, qa1, qa2, qa3, qvr, qvi);
    SBAR();
    for (int s = 0; s < 30; s += 2) {
        half4 na0, na1, na2, na3, nvr, nvi;
        load_frag(KPg, VTg, s + 2, qlane, g, na0, na1, na2, na3, nvr, nvi);
        SBAR();                                  // loads for s+2 pinned above
        attn_step(pa0, pa1, pa2, pa3, pvr, pvi,
                  Quh, Qul, Qu2h, Qu2l, ore, oim, m, l);
        half4 ma0, ma1, ma2, ma3, mvr, mvi;
        load_frag(KPg, VTg, s + 3, qlane, g, ma0, ma1, ma2, ma3, mvr, mvi);
        SBAR();                                  // loads for s+3 pinned above
        attn_step(qa0, qa1, qa2, qa3, qvr, qvi,
                  Quh, Qul, Qu2h, Qu2l, ore, oim, m, l);
        pa0 = na0; pa1 = na1; pa2 = na2; pa3 = na3; pvr = nvr; pvi = nvi;
        qa0 = ma0; qa1 = ma1; qa2 = ma2; qa3 = ma3; qvr = mvr; qvi = mvi;
    }
    attn_step(pa0, pa1, pa2, pa3, pvr, pvi,
              Quh, Qul, Qu2h, Qu2l, ore, oim, m, l);     // s = 30
    attn_step(qa0, qa1, qa2, qa3, qvr, qvi,
              Quh, Qul, Qu2h, Qu2l, ore, oim, m, l);     // s = 31

    {   // tail: key 512 only (rows 513..527 zeroed -> p underflows to 0)
        half4 z = {};
        half4 a0 = z, a1 = z, a2 = z, a3 = z, vfr = z, vfi = z;
        if (qlane == 0) {
            const _Float16* kr = KPg + 512 * 64 + 4 * g;
            a0 = *(const half4*)(kr);
            a1 = *(const half4*)(kr + 16);
            a2 = *(const half4*)(kr + 32);
            a3 = *(const half4*)(kr + 48);
        }
        if (g == 0) {
            vfr[0] = VTg[qlane * 520 + 512];
            vfi[0] = VTg[(16 + qlane) * 520 + 512];
        }
        attn_step(a0, a1, a2, a3, vfr, vfi,
                  Quh, Qul, Qu2h, Qu2l, ore, oim, m, l);
    }

    // ---- per-row l: sum the 4 g-group partials (intra-wave, no LDS) ----
    float lt = l;
    lt += __shfl_xor(lt, 16);
    lt += __shfl_xor(lt, 32);
    if (writer) {
        float inv = 1.f / lt;
#pragma unroll
        for (int j = 0; j < 4; ++j) {
            int c = 4 * g + j;                   // D row = channel
            if (c < CDIM)
                outspec[((size_t)(bg * CDIM + c)) * FDIM + frow] =
                    make_float2(ore[j] * inv, oim[j] * inv);
        }
    }
}

// ---------------- Kernel 4: two-for-one irfft(1024) ----------------
// Launched with 512 threads (see fft_fwd2 note).
__global__ void fft_inv2(const float2* __restrict__ spec, float* __restrict__ out) {
    __shared__ float re[1024], im[1024];
    const int s2 = blockIdx.x;                   // pair 0..1039
    const float2* Y1 = spec + (size_t)(2 * s2) * FDIM;
    const float2* Y2 = Y1 + FDIM;
    for (int t = threadIdx.x; t < 1024; t += blockDim.x) {
        float a, b, c, d;
        if (t <= 512) {
            float2 y1 = Y1[t], y2 = Y2[t];
            bool edge = (t == 0) | (t == 512);
            a = y1.x; b = edge ? 0.f : y1.y;
            c = y2.x; d = edge ? 0.f : y2.y;
        } else {
            float2 y1 = Y1[1024 - t], y2 = Y2[1024 - t];
            a = y1.x; b = -y1.y;
            c = y2.x; d = -y2.y;
        }
        unsigned r = bitrev10(t);
        re[r] = a - d;
        im[r] = b + c;
    }
    __syncthreads();
    for (int s = 0; s < 10; ++s) {
        int half = 1 << s;
        for (int j = threadIdx.x; j < 512; j += blockDim.x) {
            int grp = j >> s;
            int pos = j & (half - 1);
            int i1 = (grp << (s + 1)) + pos;
            int i2 = i1 + half;
            float ang = (float)M_PI * (float)pos / (float)half;   // +sign = inverse
            float sw, cw; __sincosf(ang, &sw, &cw);
            float xr = re[i2], xi = im[i2];
            float tr = cw * xr - sw * xi;
            float ti = cw * xi + sw * xr;
            float ur = re[i1], ui = im[i1];
            re[i1] = ur + tr; im[i1] = ui + ti;
            re[i2] = ur - tr; im[i2] = ui - ti;
        }
        __syncthreads();
    }
    const float scale = 1.0f / 1024.0f;
    float* o1 = out + (size_t)(2 * s2) * TDIM;
    for (int t = threadIdx.x; t < 1024; t += blockDim.x) {
        o1[t]        = re[t] * scale;
        o1[TDIM + t] = im[t] * scale;
    }
}

extern "C" void kernel_launch(void* const* d_in, const int* in_sizes, int n_in,
                              void* d_out, int out_size, void* d_ws, size_t ws_size,
                              hipStream_t stream) {
    const float* x  = (const float*)d_in[0];
    const float* wq = (const float*)d_in[1];
    const float* wk = (const float*)d_in[2];
    const float* wv = (const float*)d_in[3];
    float* out = (float*)d_out;

    const size_t n = (size_t)NROW * CDIM;        // 1,067,040 complex per buffer
    float2* xf = (float2*)d_ws;                  // x_fft, later reused as out-spectrum
    float2* q  = xf + n;                         // 8.54 MB
    _Float16* KP = (_Float16*)(q + n);           // NROW*64 halves = 10.51 MB
    _Float16* VT = KP + (size_t)NROW * 64;       // BG*2*16*520 halves = 5.32 MB

    fft_fwd2<<<BG * CDIM / 2, 512, 0, stream>>>(x, xf);
    qkv_kernel<<<(NROW * CDIM + 255) / 256, 256, 0, stream>>>(xf, wq, wk, wv, q, KP, VT);
    attn_kernel<<<BG * NCHUNK, 256, 0, stream>>>(q, KP, VT, xf /* outspec, aliases xf */);
    fft_inv2<<<BG * CDIM / 2, 512, 0, stream>>>(xf, out);
}

// Round 11
// 178.855 us; speedup vs baseline: 1.2775x; 1.2775x over previous
//
#include <hip/hip_runtime.h>
#include <math.h>

// Problem constants
#define BDIM 4
#define GDIM 40
#define CDIM 13
#define TDIM 1024
#define FDIM 513                 // T/2 + 1
#define BG   (BDIM*GDIM)         // 160
#define NROW (BG*FDIM)           // 82080 rows of [13] complex
#define NCHUNK 9                 // 9*64 = 576 >= 513 q-rows per bg
#define TK 64                    // K rows staged per LDS tile (attn)
#define QW 64                    // f-rows per qkv block

typedef _Float16 half4 __attribute__((ext_vector_type(4)));
typedef _Float16 half8 __attribute__((ext_vector_type(8)));
typedef float    f32x4 __attribute__((ext_vector_type(4)));

#define MFMA16(a, b, c) __builtin_amdgcn_mfma_f32_16x16x16f16((a), (b), (c), 0, 0, 0)

__device__ __forceinline__ unsigned bitrev10(unsigned x) { return __brev(x) >> 22; }

// ---------------- Kernel 1: two-for-one rfft(1024) ----------------
// Launched with 512 threads: 1 butterfly per thread per stage, 8 waves/block.
__global__ void fft_fwd2(const float* __restrict__ x, float2* __restrict__ xf) {
    __shared__ float re[1024], im[1024];
    const int s2 = blockIdx.x;                   // pair index, 0..1039
    const float* x1 = x + (size_t)(2 * s2) * TDIM;
    const float* x2 = x1 + TDIM;
    for (int t = threadIdx.x; t < 1024; t += blockDim.x) {
        unsigned r = bitrev10(t);
        re[r] = x1[t];
        im[r] = x2[t];
    }
    __syncthreads();
    for (int s = 0; s < 10; ++s) {
        int half = 1 << s;
        for (int j = threadIdx.x; j < 512; j += blockDim.x) {
            int grp = j >> s;
            int pos = j & (half - 1);
            int i1 = (grp << (s + 1)) + pos;
            int i2 = i1 + half;
            float ang = -(float)M_PI * (float)pos / (float)half;
            float sw, cw; __sincosf(ang, &sw, &cw);
            float xr = re[i2], xi = im[i2];
            float tr = cw * xr - sw * xi;
            float ti = cw * xi + sw * xr;
            float ur = re[i1], ui = im[i1];
            re[i1] = ur + tr; im[i1] = ui + ti;
            re[i2] = ur - tr; im[i2] = ui - ti;
        }
        __syncthreads();
    }
    const int sigA = 2 * s2, sigB = sigA + 1;
    const int bgA = sigA / CDIM, cA = sigA % CDIM;
    const int bgB = sigB / CDIM, cB = sigB % CDIM;
    for (int f = threadIdx.x; f < FDIM; f += blockDim.x) {
        int fr = (1024 - f) & 1023;
        float zr = re[f], zi = im[f];
        float wr = re[fr], wi = im[fr];
        xf[((size_t)bgA * FDIM + f) * CDIM + cA] =
            make_float2(0.5f * (zr + wr), 0.5f * (zi - wi));
        xf[((size_t)bgB * FDIM + f) * CDIM + cB] =
            make_float2(0.5f * (zi + wi), 0.5f * (wr - zr));
    }
}

// ---------------- Kernel 2: Q/K/V projections (coalesced-write restructure) ----------------
// Old version emitted ~16 MB of 2-byte scattered stores (KP: 4x2B @128B stride; VT:
// 2x2B @1040B stride — an element-wise transpose). New: one block per (bg, 64-row
// chunk). Stage xf rows + all three weight matrices in LDS, compute identically,
// assemble KP/VT tiles in LDS (row stride 72 halves to spread banks), then write
// back with 16B coalesced stores (KP rows 128B contiguous; VT transpose done in LDS
// so global rows become 128B contiguous runs). Math identical to old qkv.
// LDS: 6656 + 2028 + 9216 + 4608 = 22.5 KB.
__global__ __launch_bounds__(256) void qkv_kernel(const float2* __restrict__ xf,
                           const float* __restrict__ wq,
                           const float* __restrict__ wk,
                           const float* __restrict__ wv,
                           float2* __restrict__ q,
                           _Float16* __restrict__ KP,
                           _Float16* __restrict__ VT) {
    __shared__ float2   Xs[QW * CDIM];           // staged xf rows
    __shared__ float    Ws[3 * CDIM * CDIM];     // wq | wk | wv
    __shared__ _Float16 KPs[QW * 72];            // KP tile, padded stride
    __shared__ _Float16 VTs[32 * 72];            // VT tile (pc = part*16+c, j), padded

    const int bg    = blockIdx.x / NCHUNK;
    const int ch    = blockIdx.x % NCHUNK;
    const int f0    = ch * QW;
    const int nrows = min(QW, FDIM - f0);        // 64, or 1 for ch==8
    const int tid   = threadIdx.x;
    const int nitems = nrows * CDIM;

    for (int idx = tid; idx < nitems; idx += 256)
        Xs[idx] = xf[((size_t)bg * FDIM + f0) * CDIM + idx];
    for (int idx = tid; idx < 3 * 169; idx += 256)
        Ws[idx] = (idx < 169) ? wq[idx] : ((idx < 338) ? wk[idx - 169] : wv[idx - 338]);
    // zero VT c-rows 13..15 / 29..31 (attn reads them; results discarded, keep finite)
    for (int z = tid; z < 6 * QW; z += 256) {
        int rr = z >> 6, jj = z & 63;
        int pc = (rr < 3) ? (13 + rr) : (29 + (rr - 3));
        VTs[pc * 72 + jj] = (_Float16)0.f;
    }
    __syncthreads();

    for (int item = tid; item < nitems; item += 256) {
        int row = item / CDIM;
        int i   = item - row * CDIM;
        const float2* xrow = &Xs[row * CDIM];
        float qr = 0, qi = 0, kr = 0, ki = 0, vr = 0, vi = 0;
#pragma unroll
        for (int c = 0; c < CDIM; ++c) {
            float2 xc = xrow[c];
            float a = Ws[c * CDIM + i];       qr += xc.x * a; qi += xc.y * a;
            float b = Ws[169 + c * CDIM + i]; kr += xc.x * b; ki += xc.y * b;
            float d = Ws[338 + c * CDIM + i]; vr += xc.x * d; vi += xc.y * d;
        }
        q[((size_t)bg * FDIM + f0) * CDIM + item] = make_float2(qr, qi);  // coalesced
        _Float16* kp = KPs + row * 72;
        _Float16 h0 = (_Float16)kr, h1 = (_Float16)ki;
        kp[i]      = h0;
        kp[13 + i] = h1;
        kp[32 + i] = (_Float16)(kr - (float)h0);
        kp[45 + i] = (_Float16)(ki - (float)h1);
        if (i == 12) {   // zero pad halves 26..31 and 58..63 (LDS, 4B-aligned)
            *(unsigned*)(kp + 26) = 0u; *(unsigned*)(kp + 28) = 0u; *(unsigned*)(kp + 30) = 0u;
            *(unsigned*)(kp + 58) = 0u; *(unsigned*)(kp + 60) = 0u; *(unsigned*)(kp + 62) = 0u;
        }
        VTs[i * 72 + row]        = (_Float16)vr;   // part 0, c = i
        VTs[(16 + i) * 72 + row] = (_Float16)vi;   // part 1
    }
    __syncthreads();

    // ---- coalesced 16B writeback ----
    _Float16* KPg = KP + ((size_t)bg * FDIM + f0) * 64;
    _Float16* VTg = VT + (size_t)bg * 2 * 16 * 520 + f0;
    if (nrows == QW) {
        for (int idx = tid; idx < QW * 8; idx += 256) {        // 512 x 16B
            int row = idx >> 3, gg = idx & 7;
            *(half8*)(KPg + row * 64 + gg * 8) = *(const half8*)(KPs + row * 72 + gg * 8);
        }
        for (int idx = tid; idx < 32 * 8; idx += 256) {        // 256 x 16B
            int pc = idx >> 3, j8 = idx & 7;
            *(half8*)(VTg + pc * 520 + j8 * 8) = *(const half8*)(VTs + pc * 72 + j8 * 8);
        }
    } else {   // tail chunk: nrows == 1 (f == 512)
        for (int idx = tid; idx < nrows * 8; idx += 256) {
            int row = idx >> 3, gg = idx & 7;
            *(half8*)(KPg + row * 64 + gg * 8) = *(const half8*)(KPs + row * 72 + gg * 8);
        }
        if (tid < 32) VTg[tid * 520] = VTs[tid * 72];
    }
}

// ---------------- Kernel 3: MFMA flash attention (exact r2 revert, 81.4 us) ----------------
// Block = 4 waves; wave w owns 16 q-rows (frow = chunk*64 + w*16 + qlane); all waves
// walk all 9 K-tiles staged in LDS (XOR-swizzled 16B granules), 2 barriers/tile.
// Scores: swapped-operand mfma 16x16x16f16, A = K-rows (fp16 hi/lo), B = Q (regs);
// Re = u.w (u=[qr,-qi]), Im = u'.w (u'=[qi,qr]); full hi/lo product incl. ll term.
// D layout: q = lane&15, kidx = 4*(lane>>4)+reg == PV B-fragment layout. PV: A = V^T.
// HISTORY (do not re-litigate): k-split +2q-sets (r3/r4) = neutral; launch_bounds
// >=5 waves/EU forces <=64-VGPR tier -> SPILL (r3: 48 VGPR/43MB, r6: 40 VGPR/61MB);
// no-LDS direct-global = 113us (latency-bound, r8); reg prefetch plain (r9) and
// sched_barrier-pinned (r10) both flat — hipcc sinks the loads. This exact kernel
// measured 81.4 us (r2): VGPR 52, MfmaUtil 30, VALUBusy 60, Occ 31.
__global__ __launch_bounds__(256, 4) void attn_kernel(const float2* __restrict__ q,
                                                      const _Float16* __restrict__ KP,
                                                      const _Float16* __restrict__ VT,
                                                      float2* __restrict__ outspec) {
    __shared__ __align__(16) _Float16 Klds[TK * 64];        // 8 KB, XOR-swizzled 16B granules
    __shared__ __align__(16) _Float16 VTlds[2 * 16 * 72];   // 4.6 KB, c-stride 72 halves

    const int bg    = blockIdx.x / NCHUNK;
    const int chunk = blockIdx.x % NCHUNK;
    const int tid   = threadIdx.x;
    const int w     = tid >> 6;
    const int lane  = tid & 63;
    const int qlane = lane & 15;
    const int g     = lane >> 4;
    const int frow  = chunk * 64 + w * 16 + qlane;
    const bool writer = (frow < FDIM);
    const int f     = writer ? frow : (FDIM - 1);
    const size_t rowbase = ((size_t)bg * FDIM + f) * CDIM;

    // ---- build Q fragments in registers: u = [qr,-qi], u' = [qi,qr], hi/lo split ----
    half4 uh[2], ul[2], u2h[2], u2l[2];
#pragma unroll
    for (int c01 = 0; c01 < 2; ++c01) {
#pragma unroll
        for (int j = 0; j < 4; ++j) {
            int k = c01 * 16 + 4 * g + j;
            float a = 0.f, b = 0.f;
            if (k < CDIM) {
                float2 t = q[rowbase + k];          a = t.x;  b = t.y;
            } else if (k < 2 * CDIM) {
                float2 t = q[rowbase + (k - CDIM)]; a = -t.y; b = t.x;
            }
            _Float16 ah = (_Float16)a;
            uh[c01][j]  = ah;
            ul[c01][j]  = (_Float16)(a - (float)ah);
            _Float16 bh = (_Float16)b;
            u2h[c01][j] = bh;
            u2l[c01][j] = (_Float16)(b - (float)bh);
        }
    }

    f32x4 o_re = {0.f, 0.f, 0.f, 0.f};
    f32x4 o_im = {0.f, 0.f, 0.f, 0.f};
    float m = -INFINITY, l = 0.f;

    const _Float16* __restrict__ KPg = KP + (size_t)bg * FDIM * 64;
    const _Float16* __restrict__ VTg = VT + (size_t)bg * 2 * 16 * 520;

    for (int t0 = 0; t0 < FDIM; t0 += TK) {          // 9 tiles of 64 K-rows
        __syncthreads();                             // previous tile fully consumed
        // ---- stage K rows (2 x 16B granules per thread, XOR-swizzled placement) ----
#pragma unroll
        for (int hh = 0; hh < 2; ++hh) {
            int gr  = tid + hh * 256;                // 0..511
            int krw = gr >> 3, gg = gr & 7;
            half8 val;
#pragma unroll
            for (int e = 0; e < 8; ++e) val[e] = (_Float16)0.f;
            int grow = t0 + krw;
            if (grow < FDIM)
                val = *(const half8*)(KPg + (size_t)grow * 64 + gg * 8);
            *(half8*)(Klds + krw * 64 + ((gg ^ (krw & 7)) << 3)) = val;
        }
        // ---- stage V^T (1 x 16B granule per thread) ----
        {
            int gk = tid & 7, cc = (tid >> 3) & 15, part = tid >> 7;
            int rb = t0 + gk * 8;
            half8 val;
#pragma unroll
            for (int e = 0; e < 8; ++e) val[e] = (_Float16)0.f;
            if (rb < FDIM) {
                val = *(const half8*)(VTg + ((size_t)(part * 16 + cc)) * 520 + rb);
                if (rb + 8 > FDIM) {                 // straddle: zero tail (keeps 0*p, no NaN)
#pragma unroll
                    for (int e = 0; e < 8; ++e) if (rb + e >= FDIM) val[e] = (_Float16)0.f;
                }
            }
            *(half8*)(VTlds + (part * 16 + cc) * 72 + gk * 8) = val;
        }
        __syncthreads();

        // ---- 4 sub-tiles of 16 keys ----
#pragma unroll
        for (int sub = 0; sub < 4; ++sub) {
            const int arow = sub * 16 + qlane;       // K-row supplied by this lane (A-frag m)
            const int rx   = arow & 7;
            const _Float16* kr = Klds + arow * 64;
#define KFRAG(h) (*(const half4*)(kr + (((((h) >> 3)) ^ rx) << 3) + ((h) & 7)))
            half4 wh0 = KFRAG(4 * g);
            half4 wh1 = KFRAG(16 + 4 * g);
            half4 wl0 = KFRAG(32 + 4 * g);
            half4 wl1 = KFRAG(48 + 4 * g);
#undef KFRAG
            f32x4 sre = {0.f, 0.f, 0.f, 0.f};
            f32x4 sim = {0.f, 0.f, 0.f, 0.f};
            sre = MFMA16(wh0, uh[0], sre);
            sre = MFMA16(wh1, uh[1], sre);
            sre = MFMA16(wl0, uh[0], sre);
            sre = MFMA16(wl1, uh[1], sre);
            sre = MFMA16(wh0, ul[0], sre);
            sre = MFMA16(wh1, ul[1], sre);
            sre = MFMA16(wl0, ul[0], sre);           // ll term: keeps score err at fp32 level
            sre = MFMA16(wl1, ul[1], sre);
            sim = MFMA16(wh0, u2h[0], sim);
            sim = MFMA16(wh1, u2h[1], sim);
            sim = MFMA16(wl0, u2h[0], sim);
            sim = MFMA16(wl1, u2h[1], sim);
            sim = MFMA16(wh0, u2l[0], sim);
            sim = MFMA16(wh1, u2l[1], sim);
            sim = MFMA16(wl0, u2l[0], sim);
            sim = MFMA16(wl1, u2l[1], sim);

            // |score| ; this lane holds scores for its q at kidx = sub*16 + 4g + j
            float s0 = sqrtf(fmaf(sre[0], sre[0], sim[0] * sim[0]));
            float s1 = sqrtf(fmaf(sre[1], sre[1], sim[1] * sim[1]));
            float s2 = sqrtf(fmaf(sre[2], sre[2], sim[2] * sim[2]));
            float s3 = sqrtf(fmaf(sre[3], sre[3], sim[3] * sim[3]));
            float tmax = fmaxf(fmaxf(s0, s1), fmaxf(s2, s3));
            tmax = fmaxf(tmax, __shfl_xor(tmax, 16));
            tmax = fmaxf(tmax, __shfl_xor(tmax, 32));
            float mnew  = fmaxf(m, tmax);
            float alpha = __expf(m - mnew);          // exp(-inf)=0 covers first tile
            m = mnew;
            l *= alpha;
            o_re *= alpha;
            o_im *= alpha;
            float p0 = __expf(s0 - m);
            float p1 = __expf(s1 - m);
            float p2 = __expf(s2 - m);
            float p3 = __expf(s3 - m);
            l += (p0 + p1) + (p2 + p3);
            half4 pk;
            pk[0] = (_Float16)p0; pk[1] = (_Float16)p1;
            pk[2] = (_Float16)p2; pk[3] = (_Float16)p3;

            const int voff = sub * 16 + 4 * g;
            half4 vfr = *(const half4*)(VTlds + qlane * 72 + voff);
            half4 vfi = *(const half4*)(VTlds + (16 + qlane) * 72 + voff);
            o_re = MFMA16(vfr, pk, o_re);
            o_im = MFMA16(vfi, pk, o_im);
        }
    }

    // ---- merge partial l across the 4 k-groups of each q-column ----
    l += __shfl_xor(l, 16);
    l += __shfl_xor(l, 32);
    if (writer) {
        float inv = 1.f / l;
#pragma unroll
        for (int j = 0; j < 4; ++j) {
            int c = 4 * g + j;                       // D row = channel
            if (c < CDIM)
                outspec[((size_t)(bg * CDIM + c)) * FDIM + frow] =
                    make_float2(o_re[j] * inv, o_im[j] * inv);
        }
    }
}

// ---------------- Kernel 4: two-for-one irfft(1024) ----------------
// Launched with 512 threads (see fft_fwd2 note).
__global__ void fft_inv2(const float2* __restrict__ spec, float* __restrict__ out) {
    __shared__ float re[1024], im[1024];
    const int s2 = blockIdx.x;                   // pair 0..1039
    const float2* Y1 = spec + (size_t)(2 * s2) * FDIM;
    const float2* Y2 = Y1 + FDIM;
    for (int t = threadIdx.x; t < 1024; t += blockDim.x) {
        float a, b, c, d;
        if (t <= 512) {
            float2 y1 = Y1[t], y2 = Y2[t];
            bool edge = (t == 0) | (t == 512);
            a = y1.x; b = edge ? 0.f : y1.y;
            c = y2.x; d = edge ? 0.f : y2.y;
        } else {
            float2 y1 = Y1[1024 - t], y2 = Y2[1024 - t];
            a = y1.x; b = -y1.y;
            c = y2.x; d = -y2.y;
        }
        unsigned r = bitrev10(t);
        re[r] = a - d;
        im[r] = b + c;
    }
    __syncthreads();
    for (int s = 0; s < 10; ++s) {
        int half = 1 << s;
        for (int j = threadIdx.x; j < 512; j += blockDim.x) {
            int grp = j >> s;
            int pos = j & (half - 1);
            int i1 = (grp << (s + 1)) + pos;
            int i2 = i1 + half;
            float ang = (float)M_PI * (float)pos / (float)half;   // +sign = inverse
            float sw, cw; __sincosf(ang, &sw, &cw);
            float xr = re[i2], xi = im[i2];
            float tr = cw * xr - sw * xi;
            float ti = cw * xi + sw * xr;
            float ur = re[i1], ui = im[i1];
            re[i1] = ur + tr; im[i1] = ui + ti;
            re[i2] = ur - tr; im[i2] = ui - ti;
        }
        __syncthreads();
    }
    const float scale = 1.0f / 1024.0f;
    float* o1 = out + (size_t)(2 * s2) * TDIM;
    for (int t = threadIdx.x; t < 1024; t += blockDim.x) {
        o1[t]        = re[t] * scale;
        o1[TDIM + t] = im[t] * scale;
    }
}

extern "C" void kernel_launch(void* const* d_in, const int* in_sizes, int n_in,
                              void* d_out, int out_size, void* d_ws, size_t ws_size,
                              hipStream_t stream) {
    const float* x  = (const float*)d_in[0];
    const float* wq = (const float*)d_in[1];
    const float* wk = (const float*)d_in[2];
    const float* wv = (const float*)d_in[3];
    float* out = (float*)d_out;

    const size_t n = (size_t)NROW * CDIM;        // 1,067,040 complex per buffer
    float2* xf = (float2*)d_ws;                  // x_fft, later reused as out-spectrum
    float2* q  = xf + n;                         // 8.54 MB
    _Float16* KP = (_Float16*)(q + n);           // NROW*64 halves = 10.51 MB
    _Float16* VT = KP + (size_t)NROW * 64;       // BG*2*16*520 halves = 5.32 MB

    fft_fwd2<<<BG * CDIM / 2, 512, 0, stream>>>(x, xf);
    qkv_kernel<<<BG * NCHUNK, 256, 0, stream>>>(xf, wq, wk, wv, q, KP, VT);
    attn_kernel<<<BG * NCHUNK, 256, 0, stream>>>(q, KP, VT, xf /* outspec, aliases xf */);
    fft_inv2<<<BG * CDIM / 2, 512, 0, stream>>>(xf, out);
}